// Round 4
// baseline (367.375 us; speedup 1.0000x reference)
//
#include <hip/hip_runtime.h>

#define BATCH   4
#define SEQLEN  4096
#define NHEADS  32
#define PDIM    64
#define NDIM    16
#define CHUNK   64
#define NCHUNK  64   // SEQLEN / CHUNK
#define PQ      16   // p-quarter owned by each block

typedef short v8s __attribute__((ext_vector_type(8)));
typedef float v4f __attribute__((ext_vector_type(4)));

union V8U { v8s s; unsigned u[4]; };

__device__ __forceinline__ short f2bf(float f) {
    union { float f; unsigned u; } x; x.f = f;
    unsigned r = (x.u + 0x7FFFu + ((x.u >> 16) & 1u)) >> 16;  // RNE
    return (short)r;
}
__device__ __forceinline__ float bf2f(short s) {
    union { unsigned u; float f; } x; x.u = ((unsigned)(unsigned short)s) << 16;
    return x.f;
}
// HW packed f32->bf16 (RNE), 2 elems/inst.
__device__ __forceinline__ unsigned cvt_pk_bf16(float lo, float hi) {
    unsigned r;
    asm("v_cvt_pk_bf16_f32 %0, %1, %2" : "=v"(r) : "v"(lo), "v"(hi));
    return r;
}

__device__ __forceinline__ float wave_iscan(float v, int lane) {
#pragma unroll
    for (int d = 1; d < 64; d <<= 1) {
        float o = __shfl_up(v, (unsigned)d, 64);
        if (lane >= d) v += o;
    }
    return v;
}

// ---------------------------------------------------------------------------
// Fused SSD kernel v5.
// Grid (4 p-quarters, NHEADS, BATCH) = 512 blocks -> 2 blocks/CU (latency
// overlap across independent chunk pipelines).  512 threads, 8 waves:
//   waves 4,5: X quarter-tile (kk half each), transposed global load ->
//              xF (raw bf16) + xSF (decay-weighted) MFMA A-frags, HW cvt_pk.
//   wave 6:    B row/lane -> bFq (QK B-frags, vectorized) + bFs (state frags).
//   wave 7:    C row/lane -> cFq.
//   waves 0-3: consumers — QK^T MFMA -> G via f32 LDS rows -> Y MFMAs;
//              wave 0 runs the state MFMAs + in-register scan S.
// Whole-sequence A-cumsum precomputed ONCE into sCumAll (hierarchical scan);
// all per-iter uses are within-chunk differences of the global cumsum.
// One barrier per chunk; double-buffered frag LDS.
// ---------------------------------------------------------------------------
__global__ __launch_bounds__(512) void k_fused(
    const float* __restrict__ X, const float* __restrict__ A,
    const float* __restrict__ Bm, const float* __restrict__ Cm,
    float* __restrict__ Y)
{
    const int ph = blockIdx.x, hh = blockIdx.y, bb = blockIdx.z;
    const int tid = threadIdx.x;
    const int lane = tid & 63;
    const int wv = tid >> 6;           // 0..7
    const int W = wv & 3;
    const int qq = lane >> 4, nn = lane & 15;

    __shared__ __align__(16) float sCumAll[SEQLEN];   // 16 KB, whole (b,h) cumsum
    __shared__ __align__(16) short xF [2][2][64][8];  // 4 KB
    __shared__ __align__(16) short xSF[2][2][64][8];  // 4 KB
    __shared__ __align__(16) short cFq[2][2048];      // 8 KB (K=n zero-pad 16->32)
    __shared__ __align__(16) short bFq[2][2048];      // 8 KB
    __shared__ __align__(16) short bFs[2][1024];      // 4 KB
    __shared__ __align__(16) short sF [2][512];       // 2 KB (1 p-tile, dbuf)
    __shared__ __align__(16) float gRaw[CHUNK][68];   // 17.4 KB
    __shared__ float wtot[8];
    // total ~63 KB -> 2 blocks/CU

    {   // zero-init: qk-frag K-pad regions + sF (S_prev = 0 for chunk 0)
        const v8s z8 = {0,0,0,0,0,0,0,0};
        ((v8s*)cFq)[tid] = z8;                 // 512 v8s = both buffers
        ((v8s*)bFq)[tid] = z8;
        if (tid < 128) ((v8s*)sF)[tid] = z8;
    }

    // ---- whole-sequence A cumsum (one-time, all 8 waves) ----
    {
        const float* Ab = A + (size_t)bb * SEQLEN * NHEADS + hh;
        const int tb = wv * 512 + lane * 8;
        float av[8];
#pragma unroll
        for (int j = 0; j < 8; ++j) av[j] = Ab[(size_t)(tb + j) * NHEADS];
        float s8 = 0.f;
#pragma unroll
        for (int j = 0; j < 8; ++j) s8 += av[j];
        const float pre = wave_iscan(s8, lane);
        if (lane == 63) wtot[wv] = pre;
        __syncthreads();
        float base = 0.f;
#pragma unroll
        for (int w = 0; w < 7; ++w) if (w < wv) base += wtot[w];
        float c = base + pre - s8;             // exclusive prefix of this lane
#pragma unroll
        for (int j = 0; j < 8; ++j) { c += av[j]; sCumAll[tb + j] = c; }
        __syncthreads();
    }

    auto stage = [&](int c, int buf) {
        const int t0c = bb * SEQLEN + c * CHUNK;
        const float* gcc = &sCumAll[c * CHUNK];
        if (wv <= 5) {                          // X quarter-tile, kk half
            const int kk = wv - 4;
            const int trow = kk * 32 + qq * 8;
            const float* xb = X + ((size_t)(t0c + trow) * NHEADS + hh) * PDIM + ph * PQ + nn;
            float xv[8];
#pragma unroll
            for (int j = 0; j < 8; ++j) xv[j] = xb[(size_t)j * (NHEADS * PDIM)];
            const float gtot = gcc[63];
            float ex[8];
#pragma unroll
            for (int j = 0; j < 8; ++j) ex[j] = __expf(gtot - gcc[trow + j]);
            V8U xf, xs;
#pragma unroll
            for (int j2 = 0; j2 < 4; ++j2) {
                xf.u[j2] = cvt_pk_bf16(xv[2*j2], xv[2*j2+1]);
                xs.u[j2] = cvt_pk_bf16(xv[2*j2] * ex[2*j2], xv[2*j2+1] * ex[2*j2+1]);
            }
            *(v8s*)&xF [buf][kk][lane][0] = xf.s;
            *(v8s*)&xSF[buf][kk][lane][0] = xs.s;
        } else if (wv == 6) {                   // B row per lane
            const float* bp = &Bm[((size_t)(t0c + lane) * NHEADS + hh) * NDIM];
            const float4 v0 = *(const float4*)(bp);
            const float4 v1 = *(const float4*)(bp + 4);
            const float4 v2 = *(const float4*)(bp + 8);
            const float4 v3 = *(const float4*)(bp + 12);
            V8U lo, hi;
            lo.u[0] = cvt_pk_bf16(v0.x, v0.y); lo.u[1] = cvt_pk_bf16(v0.z, v0.w);
            lo.u[2] = cvt_pk_bf16(v1.x, v1.y); lo.u[3] = cvt_pk_bf16(v1.z, v1.w);
            hi.u[0] = cvt_pk_bf16(v2.x, v2.y); hi.u[1] = cvt_pk_bf16(v2.z, v2.w);
            hi.u[2] = cvt_pk_bf16(v3.x, v3.y); hi.u[3] = cvt_pk_bf16(v3.z, v3.w);
            const int off0 = ((lane >> 4) * 64 + (lane & 15)) * 8;
            *(v8s*)&bFq[buf][off0]       = lo.s;     // n = 0..7
            *(v8s*)&bFq[buf][off0 + 128] = hi.s;     // n = 8..15
            const int bs = ((lane >> 5) * 64 + ((lane >> 3) & 3) * 16) * 8 + (lane & 7);
#pragma unroll
            for (int n = 0; n < 8; ++n) bFs[buf][bs + n * 8]       = lo.s[n];
#pragma unroll
            for (int n = 0; n < 8; ++n) bFs[buf][bs + (n + 8) * 8] = hi.s[n];
        } else {                                // wv == 7: C row per lane
            const float* cp = &Cm[((size_t)(t0c + lane) * NHEADS + hh) * NDIM];
            const float4 v0 = *(const float4*)(cp);
            const float4 v1 = *(const float4*)(cp + 4);
            const float4 v2 = *(const float4*)(cp + 8);
            const float4 v3 = *(const float4*)(cp + 12);
            V8U lo, hi;
            lo.u[0] = cvt_pk_bf16(v0.x, v0.y); lo.u[1] = cvt_pk_bf16(v0.z, v0.w);
            lo.u[2] = cvt_pk_bf16(v1.x, v1.y); lo.u[3] = cvt_pk_bf16(v1.z, v1.w);
            hi.u[0] = cvt_pk_bf16(v2.x, v2.y); hi.u[1] = cvt_pk_bf16(v2.z, v2.w);
            hi.u[2] = cvt_pk_bf16(v3.x, v3.y); hi.u[3] = cvt_pk_bf16(v3.z, v3.w);
            const int off0 = ((lane >> 4) * 64 + (lane & 15)) * 8;
            *(v8s*)&cFq[buf][off0]       = lo.s;
            *(v8s*)&cFq[buf][off0 + 128] = hi.s;
        }
    };

    if (wv >= 4) stage(0, 0);
    __syncthreads();

    v4f S = {0.f, 0.f, 0.f, 0.f};     // running scanned state (wave 0)
    const v4f zero = {0.f, 0.f, 0.f, 0.f};

#pragma unroll 1
    for (int k = 0; k < NCHUNK; ++k) {
        const int cur = k & 1;
        if (wv >= 4) {
            if (k + 1 < NCHUNK) stage(k + 1, cur ^ 1);
        } else {
            const int t0c = bb * SEQLEN + k * CHUNK;
            const float* gc = &sCumAll[k * CHUNK];
            const float gbase = (k == 0) ? 0.f : gc[-1];
            float tcum[4];
#pragma unroll
            for (int r = 0; r < 4; ++r) tcum[r] = gc[W * 16 + qq * 4 + r];
            const v8s cfrag = *(const v8s*)&cFq[cur][(W * 64 + lane) * 8];

            // --- QK^T MFMA -> G (f32 rows, 2-way/free bank pattern) ---
#pragma unroll
            for (int st = 0; st < 4; ++st) {
                if (st <= W) {
                    const v8s bfrag = *(const v8s*)&bFq[cur][(st * 64 + lane) * 8];
                    v4f acc = __builtin_amdgcn_mfma_f32_16x16x32_bf16(cfrag, bfrag, zero, 0, 0, 0);
                    const float cums = gc[st * 16 + nn];
#pragma unroll
                    for (int r = 0; r < 4; ++r) {
                        const int t = W * 16 + qq * 4 + r;
                        const int s = st * 16 + nn;
                        gRaw[t][s] = (t >= s) ? acc[r] * __expf(tcum[r] - cums) : 0.f;
                    }
                }
            }
            if (W == 0) {
#pragma unroll
                for (int r = 0; r < 4; ++r) gRaw[qq * 4 + r][16 + nn] = 0.f;
            } else if (W == 2) {
#pragma unroll
                for (int r = 0; r < 4; ++r) gRaw[32 + qq * 4 + r][48 + nn] = 0.f;
            }

            // --- cefrag = C * exp(local cum_t) ---
            const float et = __expf(gc[W * 16 + nn] - gbase);
            V8U cef;
#pragma unroll
            for (int j2 = 0; j2 < 4; ++j2)
                cef.u[j2] = cvt_pk_bf16(bf2f(cfrag[2*j2]) * et, bf2f(cfrag[2*j2+1]) * et);

            // --- G A-frags: row-contiguous reads + HW pack ---
            V8U ga0u, ga1u;
            {
                const float* gr = &gRaw[W * 16 + nn][qq * 8];          // kk=0
#pragma unroll
                for (int j2 = 0; j2 < 4; ++j2) ga0u.u[j2] = cvt_pk_bf16(gr[2*j2], gr[2*j2+1]);
            }
            const bool usekk1 = (W >= 2);
            if (usekk1) {
                const float* gr = &gRaw[W * 16 + nn][32 + qq * 8];     // kk=1
#pragma unroll
                for (int j2 = 0; j2 < 4; ++j2) ga1u.u[j2] = cvt_pk_bf16(gr[2*j2], gr[2*j2+1]);
            }

            // --- Y = Y_off (Ce x S_prev^T) + Y_diag (G x X) ---
            const v8s sfrag = *(const v8s*)&sF[cur][lane * 8];
            v4f a = __builtin_amdgcn_mfma_f32_16x16x32_bf16(cef.s, sfrag, zero, 0, 0, 0);
            const v8s x0 = *(const v8s*)&xF[cur][0][lane][0];
            a = __builtin_amdgcn_mfma_f32_16x16x32_bf16(ga0u.s, x0, a, 0, 0, 0);
            if (usekk1) {
                const v8s x1 = *(const v8s*)&xF[cur][1][lane][0];
                a = __builtin_amdgcn_mfma_f32_16x16x32_bf16(ga1u.s, x1, a, 0, 0, 0);
            }
#pragma unroll
            for (int r = 0; r < 4; ++r) {
                const int t = W * 16 + qq * 4 + r;
                Y[((size_t)(t0c + t) * NHEADS + hh) * PDIM + ph * PQ + nn] = a[r];
            }

            // --- chunk state + scan (wave 0 only: single 16x16 p-tile) ---
            if (W == 0) {
                const v8s a0 = *(const v8s*)&xSF[cur][0][lane][0];
                const v8s a1 = *(const v8s*)&xSF[cur][1][lane][0];
                const v8s b0 = *(const v8s*)&bFs[cur][(0 * 64 + lane) * 8];
                const v8s b1 = *(const v8s*)&bFs[cur][(1 * 64 + lane) * 8];
                v4f sa = __builtin_amdgcn_mfma_f32_16x16x32_bf16(a0, b0, zero, 0, 0, 0);
                sa = __builtin_amdgcn_mfma_f32_16x16x32_bf16(a1, b1, sa, 0, 0, 0);
                const float Et = __expf(gc[63] - gbase);
#pragma unroll
                for (int r = 0; r < 4; ++r) S[r] = Et * S[r] + sa[r];
                short* d = &sF[cur ^ 1][0];
#pragma unroll
                for (int r = 0; r < 4; ++r)
                    d[((nn >> 3) * 16 + qq * 4 + r) * 8 + (nn & 7)] = f2bf(S[r]);
            }
        }
        __syncthreads();
    }
}

// ---------------------------------------------------------------------------
extern "C" void kernel_launch(void* const* d_in, const int* in_sizes, int n_in,
                              void* d_out, int out_size, void* d_ws, size_t ws_size,
                              hipStream_t stream) {
    const float* X  = (const float*)d_in[0];
    const float* A  = (const float*)d_in[1];
    const float* Bm = (const float*)d_in[2];
    const float* Cm = (const float*)d_in[3];
    float* Y = (float*)d_out;
    (void)d_ws; (void)ws_size;

    dim3 grid(4, NHEADS, BATCH);
    k_fused<<<grid, 512, 0, stream>>>(X, A, Bm, Cm, Y);
}

// Round 6
// 308.271 us; speedup vs baseline: 1.1917x; 1.1917x over previous
//
#include <hip/hip_runtime.h>

#define BATCH   4
#define SEQLEN  4096
#define NHEADS  32
#define PDIM    64
#define NDIM    16
#define CHUNK   64
#define NCHUNK  64   // SEQLEN / CHUNK
#define PHALF   32

typedef short v8s __attribute__((ext_vector_type(8)));
typedef float v4f __attribute__((ext_vector_type(4)));

union V8U { v8s s; unsigned u[4]; };

__device__ __forceinline__ short f2bf(float f) {
    union { float f; unsigned u; } x; x.f = f;
    unsigned r = (x.u + 0x7FFFu + ((x.u >> 16) & 1u)) >> 16;  // RNE
    return (short)r;
}
__device__ __forceinline__ float bf2f(short s) {
    union { unsigned u; float f; } x; x.u = ((unsigned)(unsigned short)s) << 16;
    return x.f;
}
// HW packed f32->bf16 (RNE), 2 elems/inst.
__device__ __forceinline__ unsigned cvt_pk_bf16(float lo, float hi) {
    unsigned r;
    asm("v_cvt_pk_bf16_f32 %0, %1, %2" : "=v"(r) : "v"(lo), "v"(hi));
    return r;
}

__device__ __forceinline__ float wave_iscan(float v, int lane) {
#pragma unroll
    for (int d = 1; d < 64; d <<= 1) {
        float o = __shfl_up(v, (unsigned)d, 64);
        if (lane >= d) v += o;
    }
    return v;
}

// ---------------------------------------------------------------------------
// Fused SSD kernel v7 = v6 pair-pipeline with CONVERGED barriers.
// Grid (2 p-halves, NHEADS, BATCH) = 256 blocks, 8 waves.
// Per iteration (chunks k, k+1):
//   slot 1: producers stage(k+2) | consumers Phase A:
//            chunk-k G (own strip W) + chunk-(k+1) G (strip 3-W, balances the
//            causal mask to 5 QK tiles/wave) + chunk-k Y + BOTH state updates
//            (S in regs, waves 0-1) + sF publishes.
//   __syncthreads()  (converged)
//   slot 2: producers stage(k+3) | consumers Phase B: chunk-(k+1) Y.
//   __syncthreads()  (converged)
// Whole-sequence A-cumsum precomputed once in sCumAll (round-4, verified).
// Quad-buffered frag LDS; buffers read {k,k+1}&3, written {k+2,k+3}&3 —
// disjoint mod 4.  s_setprio(1) wraps consumer phases (T5).
// ---------------------------------------------------------------------------
__global__ __launch_bounds__(512) void k_fused(
    const float* __restrict__ X, const float* __restrict__ A,
    const float* __restrict__ Bm, const float* __restrict__ Cm,
    float* __restrict__ Y)
{
    const int ph = blockIdx.x, hh = blockIdx.y, bb = blockIdx.z;
    const int tid = threadIdx.x;
    const int lane = tid & 63;
    const int wv = tid >> 6;           // 0..7
    const int W = wv & 3;
    const int qq = lane >> 4, nn = lane & 15;

    __shared__ __align__(16) float sCumAll[SEQLEN];   // 16 KB
    __shared__ __align__(16) short xF [4][4][64][8];  // 16 KB
    __shared__ __align__(16) short xSF[4][4][64][8];  // 16 KB
    __shared__ __align__(16) short cFq[4][2048];      // 16 KB (K=n zero-pad)
    __shared__ __align__(16) short bFq[4][2048];      // 16 KB
    __shared__ __align__(16) short bFs[4][1024];      // 8 KB
    __shared__ __align__(16) short sF [4][1024];      // 8 KB
    __shared__ __align__(16) float gRawA[CHUNK][68];  // 17.4 KB
    __shared__ __align__(16) float gRawB[CHUNK][68];  // 17.4 KB
    __shared__ float wtot[8];
    // total ~132 KB -> 1 block/CU (grid == 256 == #CUs)

    {   // zero-init qk-frag pad regions (all 4 bufs) + sF[0] (S_prev=0)
        const v8s z8 = {0,0,0,0,0,0,0,0};
        ((v8s*)cFq)[tid] = z8; ((v8s*)cFq)[tid + 512] = z8;
        ((v8s*)bFq)[tid] = z8; ((v8s*)bFq)[tid + 512] = z8;
        if (tid < 128) ((v8s*)sF)[tid] = z8;
    }

    // ---- whole-sequence A cumsum (one-time, all 8 waves) ----
    {
        const float* Ab = A + (size_t)bb * SEQLEN * NHEADS + hh;
        const int tb = wv * 512 + lane * 8;
        float av[8];
#pragma unroll
        for (int j = 0; j < 8; ++j) av[j] = Ab[(size_t)(tb + j) * NHEADS];
        float s8 = 0.f;
#pragma unroll
        for (int j = 0; j < 8; ++j) s8 += av[j];
        const float pre = wave_iscan(s8, lane);
        if (lane == 63) wtot[wv] = pre;
        __syncthreads();
        float base = 0.f;
#pragma unroll
        for (int w = 0; w < 7; ++w) if (w < wv) base += wtot[w];
        float c = base + pre - s8;             // exclusive prefix of this lane
#pragma unroll
        for (int j = 0; j < 8; ++j) { c += av[j]; sCumAll[tb + j] = c; }
        __syncthreads();
    }

    auto stage = [&](int c, int buf) {
        const int t0c = bb * SEQLEN + c * CHUNK;
        const float* gcc = &sCumAll[c * CHUNK];
        // X tile per producer wave (kk, nt), transposed load -> xF + xSF
        const int ti = wv - 4, kk = ti >> 1, nt = ti & 1;
        const int trow = kk * 32 + qq * 8;
        const float* xb = X + ((size_t)(t0c + trow) * NHEADS + hh) * PDIM
                            + ph * PHALF + nt * 16 + nn;
        float xv[8];
#pragma unroll
        for (int j = 0; j < 8; ++j) xv[j] = xb[(size_t)j * (NHEADS * PDIM)];
        const float gtot = gcc[63];
        float ex[8];
#pragma unroll
        for (int j = 0; j < 8; ++j) ex[j] = __expf(gtot - gcc[trow + j]);
        V8U xf, xs;
#pragma unroll
        for (int j2 = 0; j2 < 4; ++j2) {
            xf.u[j2] = cvt_pk_bf16(xv[2*j2], xv[2*j2+1]);
            xs.u[j2] = cvt_pk_bf16(xv[2*j2] * ex[2*j2], xv[2*j2+1] * ex[2*j2+1]);
        }
        *(v8s*)&xF [buf][kk*2+nt][lane][0] = xf.s;
        *(v8s*)&xSF[buf][kk*2+nt][lane][0] = xs.s;
        // B (both frag layouts) + C over the 256 producer threads
        const int ptid = tid & 255;
        const int r = ptid >> 2, n0 = (ptid & 3) * 4;
        const float4 bv = *(const float4*)&Bm[((size_t)(t0c + r) * NHEADS + hh) * NDIM + n0];
        const int offq = ((r >> 4) * 64 + (n0 >> 3) * 16 + (r & 15)) * 8 + (n0 & 7);
        bFq[buf][offq + 0] = f2bf(bv.x); bFq[buf][offq + 1] = f2bf(bv.y);
        bFq[buf][offq + 2] = f2bf(bv.z); bFq[buf][offq + 3] = f2bf(bv.w);
        const int kb = r >> 5, qb = (r >> 3) & 3, jj = r & 7;
        const int bs = (kb * 64 + qb * 16) * 8 + jj;
        bFs[buf][bs + (n0 + 0) * 8] = f2bf(bv.x);
        bFs[buf][bs + (n0 + 1) * 8] = f2bf(bv.y);
        bFs[buf][bs + (n0 + 2) * 8] = f2bf(bv.z);
        bFs[buf][bs + (n0 + 3) * 8] = f2bf(bv.w);
        const float4 cv = *(const float4*)&Cm[((size_t)(t0c + r) * NHEADS + hh) * NDIM + n0];
        cFq[buf][offq + 0] = f2bf(cv.x); cFq[buf][offq + 1] = f2bf(cv.y);
        cFq[buf][offq + 2] = f2bf(cv.z); cFq[buf][offq + 3] = f2bf(cv.w);
    };

    const v4f zero = {0.f, 0.f, 0.f, 0.f};

    // QK^T -> G rows for t-strip tau of one chunk (mask st <= tau)
    auto qk_g = [&](float (*gR)[68], const float* gc, int buf, int tau) -> v8s {
        const v8s cfrag = *(const v8s*)&cFq[buf][(tau * 64 + lane) * 8];
        float tc[4];
#pragma unroll
        for (int r = 0; r < 4; ++r) tc[r] = gc[tau * 16 + qq * 4 + r];
#pragma unroll
        for (int st = 0; st < 4; ++st) {
            if (st <= tau) {
                const v8s bfrag = *(const v8s*)&bFq[buf][(st * 64 + lane) * 8];
                v4f acc = __builtin_amdgcn_mfma_f32_16x16x32_bf16(cfrag, bfrag, zero, 0, 0, 0);
                const float cums = gc[st * 16 + nn];
#pragma unroll
                for (int r = 0; r < 4; ++r) {
                    const int t = tau * 16 + qq * 4 + r;
                    const int s = st * 16 + nn;
                    gR[t][s] = (t >= s) ? acc[r] * __expf(tc[r] - cums) : 0.f;
                }
            }
        }
        if (tau == 0) {
#pragma unroll
            for (int r = 0; r < 4; ++r) gR[qq * 4 + r][16 + nn] = 0.f;
        } else if (tau == 2) {
#pragma unroll
            for (int r = 0; r < 4; ++r) gR[32 + qq * 4 + r][48 + nn] = 0.f;
        }
        return cfrag;
    };

    // Y for this wave's strip W of one chunk (G already in gR)
    auto do_y = [&](float (*gR)[68], const float* gc, float gbase, int buf,
                    int t0c, v8s cfrag) {
        const float et = __expf(gc[W * 16 + nn] - gbase);
        V8U cef;
#pragma unroll
        for (int j2 = 0; j2 < 4; ++j2)
            cef.u[j2] = cvt_pk_bf16(bf2f(cfrag[2*j2]) * et, bf2f(cfrag[2*j2+1]) * et);
        V8U ga0u, ga1u;
        {
            const float* gr = &gR[W * 16 + nn][qq * 8];          // kk=0
#pragma unroll
            for (int j2 = 0; j2 < 4; ++j2) ga0u.u[j2] = cvt_pk_bf16(gr[2*j2], gr[2*j2+1]);
        }
        const bool usekk1 = (W >= 2);
        if (usekk1) {
            const float* gr = &gR[W * 16 + nn][32 + qq * 8];     // kk=1
#pragma unroll
            for (int j2 = 0; j2 < 4; ++j2) ga1u.u[j2] = cvt_pk_bf16(gr[2*j2], gr[2*j2+1]);
        }
        v4f ya[2];
#pragma unroll
        for (int nt2 = 0; nt2 < 2; ++nt2) {
            const v8s sfrag = *(const v8s*)&sF[buf][(nt2 * 64 + lane) * 8];
            v4f a = __builtin_amdgcn_mfma_f32_16x16x32_bf16(cef.s, sfrag, zero, 0, 0, 0);
            const v8s x0 = *(const v8s*)&xF[buf][0 + nt2][lane][0];
            a = __builtin_amdgcn_mfma_f32_16x16x32_bf16(ga0u.s, x0, a, 0, 0, 0);
            if (usekk1) {
                const v8s x1 = *(const v8s*)&xF[buf][2 + nt2][lane][0];
                a = __builtin_amdgcn_mfma_f32_16x16x32_bf16(ga1u.s, x1, a, 0, 0, 0);
            }
            ya[nt2] = a;
        }
#pragma unroll
        for (int r = 0; r < 4; ++r) {
            const int t = W * 16 + qq * 4 + r;
            float* yp = Y + ((size_t)(t0c + t) * NHEADS + hh) * PDIM + ph * PHALF + nn;
            yp[0]  = ya[0][r];
            yp[16] = ya[1][r];
        }
    };

    // state update for one chunk (waves 0-1), S in regs; publish to sF[pub]
    auto do_state = [&](int buf, float Et, int pub, v4f& S) {
        const v8s a0 = *(const v8s*)&xSF[buf][0 + W][lane][0];
        const v8s a1 = *(const v8s*)&xSF[buf][2 + W][lane][0];
        const v8s b0 = *(const v8s*)&bFs[buf][(0 * 64 + lane) * 8];
        const v8s b1 = *(const v8s*)&bFs[buf][(1 * 64 + lane) * 8];
        v4f sa = __builtin_amdgcn_mfma_f32_16x16x32_bf16(a0, b0, zero, 0, 0, 0);
        sa = __builtin_amdgcn_mfma_f32_16x16x32_bf16(a1, b1, sa, 0, 0, 0);
#pragma unroll
        for (int r = 0; r < 4; ++r) S[r] = Et * S[r] + sa[r];
        short* d = &sF[pub][0];
#pragma unroll
        for (int r = 0; r < 4; ++r)
            d[(W * 64 + (nn >> 3) * 16 + qq * 4 + r) * 8 + (nn & 7)] = f2bf(S[r]);
    };

    if (wv >= 4) { stage(0, 0); stage(1, 1); }
    __syncthreads();

    v4f S = {0.f, 0.f, 0.f, 0.f};     // running scanned state (waves 0-1)
    v8s cfragB = {0,0,0,0,0,0,0,0};

#pragma unroll 1
    for (int k = 0; k < NCHUNK; k += 2) {
        const int bufA = k & 3, bufB = (k + 1) & 3;
        const float* gcA = &sCumAll[k * CHUNK];
        const float* gcB = gcA + CHUNK;

        // ---- slot 1: stage(k+2) | Phase A ----
        if (wv >= 4) {
            if (k + 2 < NCHUNK) stage(k + 2, (k + 2) & 3);
        } else {
            __builtin_amdgcn_s_setprio(1);
            const float gbaseA = (k == 0) ? 0.f : gcA[-1];
            const int t0cA = bb * SEQLEN + k * CHUNK;
            const v8s cfragA = qk_g(gRawA, gcA, bufA, W);   // chunk k, own strip
            qk_g(gRawB, gcB, bufB, 3 - W);                  // chunk k+1, balanced
            do_y(gRawA, gcA, gbaseA, bufA, t0cA, cfragA);   // chunk k Y
            if (W < 2) {
                do_state(bufA, __expf(gcA[63] - gbaseA), bufB, S);        // S after k
                do_state(bufB, __expf(gcB[63] - gcA[63]), (k + 2) & 3, S);// S after k+1
            }
            __builtin_amdgcn_s_setprio(0);
        }
        __syncthreads();                                    // converged

        // ---- slot 2: stage(k+3) | Phase B ----
        if (wv >= 4) {
            if (k + 3 < NCHUNK) stage(k + 3, (k + 3) & 3);
        } else {
            __builtin_amdgcn_s_setprio(1);
            const int t0cB = bb * SEQLEN + (k + 1) * CHUNK;
            cfragB = *(const v8s*)&cFq[bufB][(W * 64 + lane) * 8];
            do_y(gRawB, gcB, gcA[63], bufB, t0cB, cfragB);  // chunk k+1 Y
            __builtin_amdgcn_s_setprio(0);
        }
        __syncthreads();                                    // converged
    }
}

// ---------------------------------------------------------------------------
extern "C" void kernel_launch(void* const* d_in, const int* in_sizes, int n_in,
                              void* d_out, int out_size, void* d_ws, size_t ws_size,
                              hipStream_t stream) {
    const float* X  = (const float*)d_in[0];
    const float* A  = (const float*)d_in[1];
    const float* Bm = (const float*)d_in[2];
    const float* Cm = (const float*)d_in[3];
    float* Y = (float*)d_out;
    (void)d_ws; (void)ws_size;

    dim3 grid(2, NHEADS, BATCH);
    k_fused<<<grid, 512, 0, stream>>>(X, A, Bm, Cm, Y);
}